// Round 6
// baseline (155.156 us; speedup 1.0000x reference)
//
#include <hip/hip_runtime.h>

#define MAX_L 2048   // max phonemes per batch for LDS cumsum
#define MAX_EPC 8    // max cum elements per thread (L <= 256*8)
#define FPB 256      // frames per block

// Fused length-regulator, run-length store streaming + XCD-aware swizzle.
// One 256-thread block per 256 output frames:
//   1) XCD swizzle: gfx950 assigns block p to XCD p%8; remap tiles so XCD x
//      serves only batches {x, x+8, ...} -> per-XCD L2 working set ~1 MiB,
//      feat row loads hit local L2 instead of re-fetching from HBM per XCD.
//   2) block computes its batch's duration cumsum in LDS (shuffle scan)
//   3) 256 threads binary-search in LDS -> sidx[256] (phoneme idx, -1 = pad)
//   4) each wave copies 64 CONTIGUOUS frames; source row held in registers,
//      reloaded only when the (scalar, readlane'd) index changes -> steady
//      state is back-to-back coalesced 1 KiB stores, memset-shaped.
__global__ __launch_bounds__(256) void lr_fused_kernel(
        const float* __restrict__ feat,
        const int* __restrict__ dur,
        const int* __restrict__ tlen,
        float* __restrict__ out,
        int BL, int BT, int D) {
    const int T = *tlen;
    const int B = BT / T;
    const int L = BL / B;
    const int vecs = D >> 2;

    __shared__ int sc[MAX_L];
    __shared__ int swsum[4];
    __shared__ int sidx[FPB];

    // ---- XCD-aware tile swizzle (perf heuristic only; identity fallback) ----
    int tile = blockIdx.x;
    if ((T % FPB) == 0 && (B & 7) == 0) {
        const int nbpb = T / FPB;                       // tiles per batch
        if (gridDim.x == (unsigned)(B * nbpb)) {
            const int x = blockIdx.x & 7;               // XCD id
            const int s = blockIdx.x >> 3;
            const int g = s / nbpb;                     // batch group on this XCD
            const int j = s - g * nbpb;                 // tile within batch
            tile = (x + 8 * g) * nbpb + j;
        }
    }

    const long frame_base0 = (long)tile * FPB;
    if (frame_base0 >= BT) return;

    const int tid  = threadIdx.x;
    const int lane = tid & 63;
    const int wv   = tid >> 6;

    long fb_ = frame_base0;
    int remaining = (int)((long)BT - frame_base0 < FPB ? (long)BT - frame_base0
                                                       : (long)FPB);

    // Segment loop (block-uniform): one iteration when T % FPB == 0.
    while (remaining > 0) {
        const int b   = (int)(fb_ / T);
        const int tt0 = (int)(fb_ - (long)b * T);
        const int seg = remaining < (T - tt0) ? remaining : (T - tt0);

        // ---- cumsum of batch b's duration row into sc ----
        __syncthreads();  // protect sc/sidx reuse across segments
        const int epc  = (L + blockDim.x - 1) / blockDim.x;
        const int base = tid * epc;
        const int* __restrict__ drow = dur + (size_t)b * L;
        int local[MAX_EPC];
        int run = 0;
#pragma unroll
        for (int e = 0; e < MAX_EPC; ++e) {
            int v = 0;
            if (e < epc && base + e < L) v = drow[base + e];
            run += v;
            local[e] = run;
        }
        int wsum = run;
#pragma unroll
        for (int off = 1; off < 64; off <<= 1) {
            int up = __shfl_up(wsum, off, 64);
            if (lane >= off) wsum += up;
        }
        if (lane == 63) swsum[wv] = wsum;
        __syncthreads();
        int wprefix = 0;
        for (int w = 0; w < wv; ++w) wprefix += swsum[w];
        const int chunk_prefix = wprefix + wsum - run;
#pragma unroll
        for (int e = 0; e < MAX_EPC; ++e)
            if (e < epc && base + e < L) sc[base + e] = chunk_prefix + local[e];
        __syncthreads();

        const int total = sc[L - 1];

        // ---- searchsorted(side='right') for this segment's frames ----
        if (tid < seg) {
            const int t = tt0 + tid;
            int p = -1;
            if (t < total) {
                int lo = 0, hi = L - 1;
                while (lo < hi) {
                    const int mid = (lo + hi) >> 1;
                    if (sc[mid] > t) hi = mid;
                    else             lo = mid + 1;
                }
                p = lo;
            }
            sidx[tid] = p;
        }
        __syncthreads();

        // ---- copy ----
        if (seg == FPB && vecs == 64) {
            // Fast path (D == 256, full segment): wave wv owns 64 contiguous
            // frames. Row index scalar via readlane; row data (1 float4/lane)
            // reloaded only on index change (~4x per 64 frames).
            const float4* __restrict__ fbp =
                (const float4*)feat + (size_t)b * L * 64;
            float4* __restrict__ op =
                (float4*)out + ((size_t)fb_ + (size_t)wv * 64) * 64 + lane;
            const int si = sidx[wv * 64 + lane];   // lane j holds frame j's idx
            int prev = -2;
            float4 v = make_float4(0.f, 0.f, 0.f, 0.f);
#pragma unroll
            for (int j = 0; j < 64; ++j) {
                const int p = __builtin_amdgcn_readlane(si, j);  // SGPR-uniform
                if (p != prev) {                                  // scalar branch
                    v = (p >= 0) ? fbp[(size_t)p * 64 + lane]
                                 : make_float4(0.f, 0.f, 0.f, 0.f);
                    prev = p;
                }
                op[(size_t)j * 64] = v;   // back-to-back 1 KiB wave stores
            }
        } else {
            // Generic fallback: wave-strided frames, lane-strided float4s.
            const float4* __restrict__ fbp =
                (const float4*)feat + (size_t)b * L * vecs;
            const float4 z = make_float4(0.f, 0.f, 0.f, 0.f);
            for (int f = wv; f < seg; f += 4) {
                const int p = sidx[f];
                float4* __restrict__ orow = (float4*)out + ((size_t)fb_ + f) * vecs;
                if (p >= 0) {
                    const float4* __restrict__ irow = fbp + (size_t)p * vecs;
                    for (int i = lane; i < vecs; i += 64) orow[i] = irow[i];
                } else {
                    for (int i = lane; i < vecs; i += 64) orow[i] = z;
                }
            }
        }

        fb_ += seg;
        remaining -= seg;
    }
}

extern "C" void kernel_launch(void* const* d_in, const int* in_sizes, int n_in,
                              void* d_out, int out_size, void* d_ws, size_t ws_size,
                              hipStream_t stream) {
    const float* feat = (const float*)d_in[0];   // [B, L, D] fp32
    const int*   dur  = (const int*)d_in[1];     // [B, L] int32
    const int*   tlen = (const int*)d_in[2];     // scalar target_length (device)

    const int BL = in_sizes[1];                  // B*L
    const int D  = in_sizes[0] / in_sizes[1];    // feature dim
    const int BT = out_size / D;                 // B*T total frames

    const int grid = (BT + FPB - 1) / FPB;       // 512 blocks for 16x8192
    lr_fused_kernel<<<grid, 256, 0, stream>>>(feat, dur, tlen, (float*)d_out,
                                              BL, BT, D);
}